// Round 12
// baseline (3336.806 us; speedup 1.0000x reference)
//
#include <hip/hip_runtime.h>
#include <stdint.h>

// BiLSTM: B=64, T=512, D=512, U=512. Two independent forward-scanned LSTMs.
// Phase 0: convert inputs/weights to fp16 (weights transposed to [n][k]).
// Phase 1: xz = x @ W + b  (MFMA fp16 GEMM, per time-chunk)
// Phase 2: persistent cooperative recurrence, DATA-AS-FLAG ring:
//   8 groups x 16 WGs x 256 thr. INTRA-XCD GROUPING: blockIdx round-robins
//   across the 8 XCDs, so gidx = bx & 7 places all 16 WGs of a group on ONE
//   XCD (shorter fabric path for every h poll/publish; correctness does not
//   depend on the mapping). ring[t] pre-filled with f16-NaN sentinel (8B
//   agent atomic stores -> ring never L2-cached). Producers publish h
//   granules via fire-and-forget 8B agent atomic stores (self-flagging).
//   Wave v polls its 4 kb-blocks with 8B agent atomic loads, stages to
//   swizzled double-buffered LDS, ONE barrier, MFMA from LDS. U fragments:
//   plain loads (compiler L2-remat; keeps VGPR <= 256 — cooperative launch
//   silently fails above that, the R4/R5/R11 lesson). xz prefetched into
//   registers at loop bottom (no global_load_lds in the loop).

typedef _Float16 f16;
typedef _Float16 f16x8 __attribute__((ext_vector_type(8)));
typedef float    f32x4 __attribute__((ext_vector_type(4)));
typedef unsigned long long u64;

typedef __attribute__((address_space(1))) const void* gas_ptr;
typedef __attribute__((address_space(3))) void* las_ptr;

__device__ inline void gl_lds16(const void* g, void* l) {
    __builtin_amdgcn_global_load_lds((gas_ptr)g, (las_ptr)l, 16, 0, 0);
}

#define SENT64 0x7F7F7F7F7F7F7F7FULL

// ---------------- conversion kernels ----------------

__global__ void k_cvt(const float* __restrict__ src, f16* __restrict__ dst, int n8) {
    int i = blockIdx.x * 256 + threadIdx.x;
    if (i >= n8) return;
    const float4* s = (const float4*)src;
    float4 a = s[2 * i], b = s[2 * i + 1];
    f16x8 o = {(f16)a.x, (f16)a.y, (f16)a.z, (f16)a.w,
               (f16)b.x, (f16)b.y, (f16)b.z, (f16)b.w};
    *(f16x8*)(dst + 8 * (size_t)i) = o;
}

// src [512][2048] f32 -> dst [2048][512] f16 (transpose)
__global__ void k_tcvt(const float* __restrict__ src, f16* __restrict__ dst) {
    int tid = blockIdx.x * 256 + threadIdx.x;   // 131072 total
    int kc = tid >> 11;
    int n  = tid & 2047;
    f16x8 o;
#pragma unroll
    for (int j = 0; j < 8; ++j)
        o[j] = (f16)src[(size_t)(kc * 8 + j) * 2048 + n];
    *(f16x8*)(dst + (size_t)n * 512 + kc * 8) = o;
}

// ---------------- ring init kernels ----------------
// All ring writes are 8B agent atomics -> ring bytes never live in L1/L2.

__global__ void k_fill(f16* __restrict__ ring, int CT, int zero0) {
    size_t i = ((size_t)blockIdx.x * 256 + threadIdx.x) * 8;   // f16 index, 16B/thread
    const size_t slot = 65536;                    // f16 per ring slot
    size_t total = (size_t)(CT + 1) * slot;
    if (i >= total) return;
    u64 fillv = SENT64;
    if (i < slot) { if (!zero0) return; fillv = 0; }
    u64* q = (u64*)(ring + i);
    __hip_atomic_store(q + 0, fillv, __ATOMIC_RELAXED, __HIP_MEMORY_SCOPE_AGENT);
    __hip_atomic_store(q + 1, fillv, __ATOMIC_RELAXED, __HIP_MEMORY_SCOPE_AGENT);
}

__global__ void k_copyslot(f16* __restrict__ ring, int CT) {
    size_t i = (size_t)(blockIdx.x * 256 + threadIdx.x) * 8;   // 65536 f16 total
    const u64* s = (const u64*)(ring + (size_t)CT * 65536 + i);
    u64 a = s[0], b = s[1];
    u64* qd = (u64*)(ring + i);
    __hip_atomic_store(qd + 0, a, __ATOMIC_RELAXED, __HIP_MEMORY_SCOPE_AGENT);
    __hip_atomic_store(qd + 1, b, __ATOMIC_RELAXED, __HIP_MEMORY_SCOPE_AGENT);
}

// ---------------- projection GEMM ----------------
// xz[d][b][tc][n] (fp16) = x16[d][b][t0+tc][:] @ WT[d][n][:] + bias[n]

__global__ __launch_bounds__(256) void k_proj(
    const f16* __restrict__ x16, const f16* __restrict__ WT,
    const float* __restrict__ bfw, const float* __restrict__ bbw,
    f16* __restrict__ xz, int t0, int CT, int lct) {
    __shared__ f16 smem[16384];
    f16* As = smem;
    f16* Bs = smem + 8192;

    const int tid = threadIdx.x;
    const int l = tid & 63, v = tid >> 6;
    const int mt = blockIdx.x, nt = blockIdx.y, d = blockIdx.z;
    const int wm = v >> 1, wn = v & 1;
    const int lr4 = l >> 4, c16 = l & 15;

    f32x4 acc[4][4];
#pragma unroll
    for (int i = 0; i < 4; ++i)
#pragma unroll
        for (int j = 0; j < 4; ++j) acc[i][j] = (f32x4)0.f;

    auto stage = [&](int kk, int buf) {
#pragma unroll
        for (int rd = 0; rd < 2; ++rd) {
            int idx = rd * 256 + tid;
            int r = idx >> 2, kp = idx & 3;
            int m = mt * 128 + r;
            int b = m >> lct, tc = m & (CT - 1);
            const f16* ga = x16 + (((size_t)(d * 64 + b) * 512 + (t0 + tc)) * 512 + kk * 32 + kp * 8);
            gl_lds16(ga, &As[buf * 4096 + (rd * 256 + v * 64) * 8]);
        }
#pragma unroll
        for (int rd = 0; rd < 2; ++rd) {
            int idx = rd * 256 + tid;
            int r = idx >> 2, kp = idx & 3;
            const f16* gb = WT + ((size_t)(d * 2048 + nt * 128 + r) * 512 + kk * 32 + kp * 8);
            gl_lds16(gb, &Bs[buf * 4096 + (rd * 256 + v * 64) * 8]);
        }
    };

    stage(0, 0);
    for (int kk = 0; kk < 16; ++kk) {
        __syncthreads();
        if (kk < 15) stage(kk + 1, (kk + 1) & 1);
        int buf = kk & 1;
        f16x8 af[4], bfr[4];
#pragma unroll
        for (int mf = 0; mf < 4; ++mf)
            af[mf] = *(const f16x8*)&As[buf * 4096 + (wm * 64 + mf * 16 + c16) * 32 + lr4 * 8];
#pragma unroll
        for (int nf = 0; nf < 4; ++nf)
            bfr[nf] = *(const f16x8*)&Bs[buf * 4096 + (wn * 64 + nf * 16 + c16) * 32 + lr4 * 8];
#pragma unroll
        for (int mf = 0; mf < 4; ++mf)
#pragma unroll
            for (int nf = 0; nf < 4; ++nf)
                acc[mf][nf] = __builtin_amdgcn_mfma_f32_16x16x32_f16(af[mf], bfr[nf], acc[mf][nf], 0, 0, 0);
    }
    __syncthreads();

    const float* bias = d ? bbw : bfw;
    float bv[4];
#pragma unroll
    for (int nf = 0; nf < 4; ++nf) bv[nf] = bias[nt * 128 + wn * 64 + nf * 16 + c16];

    f16* Cs = smem;
#pragma unroll
    for (int mf = 0; mf < 4; ++mf)
#pragma unroll
        for (int nf = 0; nf < 4; ++nf)
#pragma unroll
            for (int r = 0; r < 4; ++r) {
                int row = wm * 64 + mf * 16 + lr4 * 4 + r;
                int col = wn * 64 + nf * 16 + c16;
                Cs[row * 128 + col] = (f16)(acc[mf][nf][r] + bv[nf]);
            }
    __syncthreads();
#pragma unroll
    for (int ch = 0; ch < 8; ++ch) {
        int flat = ch * 256 + tid;
        int row = flat >> 4, cc = flat & 15;
        int m = mt * 128 + row;
        int b = m >> lct, tc = m & (CT - 1);
        f16x8 val = *(const f16x8*)&Cs[row * 128 + cc * 8];
        *(f16x8*)&xz[((size_t)(d * 64 + b) * CT + tc) * 2048 + nt * 128 + cc * 8] = val;
    }
}

// ---------------- persistent recurrence ----------------
// 128 blocks x 256 thr: block = (wg 0..15, gidx 0..7) with bx = wg*8 + gidx
// so that all 16 WGs of a group share one XCD under round-robin dispatch.
// ring slot: [group gidx][kb 0..15][row 0..15][32 units] f16 (16KB/group).

__global__ __launch_bounds__(256, 1) void k_recur(
    const f16* __restrict__ xz, const f16* __restrict__ UT,
    f16* __restrict__ ring, float* __restrict__ cbuf,
    float* __restrict__ out, int t0, int CT) {
    __shared__ __align__(16) f16 hsm[2][8192];   // double-buffered h tile, swizzled 16B slots
    __shared__ f16 wsm[4][128];

    const int tid = threadIdx.x;
    const int l = tid & 63, v = tid >> 6;
    const int bx = blockIdx.x;
    const int gidx = bx & 7;         // XCD id under round-robin dispatch
    const int wg   = bx >> 3;        // 0..15
    const int d   = gidx >> 2;
    const int grp = gidx & 3;
    const int wu0 = wg * 32;
    const int lr4 = l >> 4;          // 0..3
    const int du  = (l & 15) >> 2;   // 0..3
    const int gid = l & 3;           // gate: 0=i 1=f 2=g 3=o
    const int row16 = l & 15;

    // U fragments: plain loads; compiler remats from L2 (fastest measured
    // variant; keeps VGPR well under the 256 cooperative-launch cliff)
    f16x8 Ufr[2][16];
#pragma unroll
    for (int nf = 0; nf < 2; ++nf) {
        int nstd = gid * 512 + wu0 + v * 8 + nf * 4 + du;
#pragma unroll
        for (int kk = 0; kk < 16; ++kk)
            Ufr[nf][kk] = *(const f16x8*)&UT[((size_t)d * 2048 + nstd) * 512 + kk * 32 + lr4 * 8];
    }

    // c state (redundant across the 4 gate lanes)
    float cst[2][4];
#pragma unroll
    for (int nf = 0; nf < 2; ++nf)
#pragma unroll
        for (int r = 0; r < 4; ++r)
            cst[nf][r] = cbuf[((size_t)d * 64 + grp * 16 + lr4 * 4 + r) * 512 + (wu0 + v * 8 + nf * 4 + du)];

    // prefetch xz for tl=0 (tracked register loads; consumed at activation)
    f16x8 xzr[4];
#pragma unroll
    for (int r = 0; r < 4; ++r)
        xzr[r] = *(const f16x8*)&xz[((size_t)(d * 64 + grp * 16 + lr4 * 4 + r) * CT + 0) * 2048
                                    + gid * 512 + wu0 + v * 8];

    for (int tl = 0; tl < CT; ++tl) {
        const int gt = t0 + tl;

        // 1. data-as-flag poll: wave v owns kb 4v..4v+3, 8 u64/lane (MALL atomic loads)
        const u64* sbase = (const u64*)ring + (size_t)tl * 16384 + (size_t)gidx * 2048
                         + (size_t)(v * 4) * 128 + l * 2;
        u64 g0, g1, g2, g3, g4, g5, g6, g7;
        while (true) {
            g0 = __hip_atomic_load(sbase +   0, __ATOMIC_RELAXED, __HIP_MEMORY_SCOPE_AGENT);
            g1 = __hip_atomic_load(sbase +   1, __ATOMIC_RELAXED, __HIP_MEMORY_SCOPE_AGENT);
            g2 = __hip_atomic_load(sbase + 128, __ATOMIC_RELAXED, __HIP_MEMORY_SCOPE_AGENT);
            g3 = __hip_atomic_load(sbase + 129, __ATOMIC_RELAXED, __HIP_MEMORY_SCOPE_AGENT);
            g4 = __hip_atomic_load(sbase + 256, __ATOMIC_RELAXED, __HIP_MEMORY_SCOPE_AGENT);
            g5 = __hip_atomic_load(sbase + 257, __ATOMIC_RELAXED, __HIP_MEMORY_SCOPE_AGENT);
            g6 = __hip_atomic_load(sbase + 384, __ATOMIC_RELAXED, __HIP_MEMORY_SCOPE_AGENT);
            g7 = __hip_atomic_load(sbase + 385, __ATOMIC_RELAXED, __HIP_MEMORY_SCOPE_AGENT);
            unsigned bad = (g0 == SENT64) | (g1 == SENT64) | (g2 == SENT64) | (g3 == SENT64)
                         | (g4 == SENT64) | (g5 == SENT64) | (g6 == SENT64) | (g7 == SENT64);
            if (!__any(bad)) break;
            __builtin_amdgcn_s_sleep(1);
        }

        // 2. stage own quarter to swizzled LDS (double-buffered)
        {
            char* hw = (char*)&hsm[tl & 1][0];
            u64 gg[4][2] = {{g0, g1}, {g2, g3}, {g4, g5}, {g6, g7}};
#pragma unroll
            for (int jj = 0; jj < 4; ++jj) {
                union { u64 u[2]; f16x8 v8; } t; t.u[0] = gg[jj][0]; t.u[1] = gg[jj][1];
                int byte = (v * 4 + jj) * 1024 + l * 16;
                byte ^= ((l >> 2) & 7) << 4;
                *(f16x8*)(hw + byte) = t.v8;
            }
        }

        // 3. ONE barrier: full h tile staged
        __syncthreads();

        // 4. z = h @ U  (A-frags from LDS; B-frags remat'd by compiler)
        f32x4 acc0 = (f32x4)0.f, acc1 = (f32x4)0.f;
        const char* hb = (const char*)&hsm[tl & 1][0];
#pragma unroll
        for (int j = 0; j < 16; ++j) {
            int byte = j * 1024 + row16 * 64 + lr4 * 16;
            byte ^= (l & 7) << 4;
            f16x8 a = *(const f16x8*)(hb + byte);
            acc0 = __builtin_amdgcn_mfma_f32_16x16x32_f16(a, Ufr[0][j], acc0, 0, 0, 0);
            acc1 = __builtin_amdgcn_mfma_f32_16x16x32_f16(a, Ufr[1][j], acc1, 0, 0, 0);
        }

        // 5. z += xz (prefetched regs); own-gate activation (gate2=tanh else sigmoid)
        float act[2][4];
#pragma unroll
        for (int nf = 0; nf < 2; ++nf)
#pragma unroll
            for (int r = 0; r < 4; ++r) {
                union { f16x8 v8; u64 u[2]; } xw; xw.v8 = xzr[r];
                union { unsigned short s; f16 h; } cv;
                cv.s = (unsigned short)(xw.u[nf] >> (du * 16));
                float z = (nf ? acc1[r] : acc0[r]) + (float)cv.h;
                float zz = (gid == 2) ? 2.f * z : z;
                float r0 = 1.f / (1.f + __expf(-zz));
                act[nf][r] = (gid == 2) ? 2.f * r0 - 1.f : r0;
            }

        // 6. exchange gates among the 4 adjacent lanes; update c; gate0 computes h
#pragma unroll
        for (int nf = 0; nf < 2; ++nf)
#pragma unroll
            for (int r = 0; r < 4; ++r) {
                float a0f = act[nf][r];
                float a1f = __shfl_xor(a0f, 1);
                float a2f = __shfl_xor(a0f, 2);
                float a3f = __shfl_xor(a0f, 3);
                int mi = gid, mf_ = gid ^ 1, mg = gid ^ 2, mo = gid ^ 3;
                float iv = mi == 0 ? a0f : mi == 1 ? a1f : mi == 2 ? a2f : a3f;
                float fv = mf_ == 0 ? a0f : mf_ == 1 ? a1f : mf_ == 2 ? a2f : a3f;
                float gv = mg == 0 ? a0f : mg == 1 ? a1f : mg == 2 ? a2f : a3f;
                float ov = mo == 0 ? a0f : mo == 1 ? a1f : mo == 2 ? a2f : a3f;
                float cn = fv * cst[nf][r] + iv * gv;
                cst[nf][r] = cn;
                if (gid == 0) {
                    float th = copysignf(1.f - 2.f / (__expf(2.f * fabsf(cn)) + 1.f), cn);
                    wsm[v][(nf * 4 + du) * 16 + lr4 * 4 + r] = (f16)(ov * th);
                }
            }

        // 7. lanes 0..15 gather their batch-row; publish granules first, then out
        if (l < 16) {
            f16x8 hv8;
#pragma unroll
            for (int j = 0; j < 8; ++j) hv8[j] = wsm[v][j * 16 + l];
            f16* dst = ring + (size_t)(tl + 1) * 65536 + (size_t)gidx * 8192
                     + ((size_t)wg * 16 + l) * 32 + v * 8;
            union { u64 u[2]; f16x8 v8; } t; t.v8 = hv8;
            __hip_atomic_store((u64*)dst + 0, t.u[0], __ATOMIC_RELAXED, __HIP_MEMORY_SCOPE_AGENT);
            __hip_atomic_store((u64*)dst + 1, t.u[1], __ATOMIC_RELAXED, __HIP_MEMORY_SCOPE_AGENT);
            size_t ob = ((size_t)(grp * 16 + l) * 512 + gt) * 1024 + d * 512 + wu0 + v * 8;
            float4 o0 = {(float)hv8[0], (float)hv8[1], (float)hv8[2], (float)hv8[3]};
            float4 o1 = {(float)hv8[4], (float)hv8[5], (float)hv8[6], (float)hv8[7]};
            *(float4*)&out[ob] = o0;
            *(float4*)&out[ob + 4] = o1;
        }

        // 8. prefetch next xz (hidden under next poll)
        {
            int tn = (tl + 1 < CT) ? tl + 1 : tl;
#pragma unroll
            for (int r = 0; r < 4; ++r)
                xzr[r] = *(const f16x8*)&xz[((size_t)(d * 64 + grp * 16 + lr4 * 4 + r) * CT + tn) * 2048
                                            + gid * 512 + wu0 + v * 8];
        }
        // no end barrier: hsm double-buffered; wsm is same-wave
    }

    // persist c for next chunk
    if (gid == 0) {
#pragma unroll
        for (int nf = 0; nf < 2; ++nf)
#pragma unroll
            for (int r = 0; r < 4; ++r)
                cbuf[((size_t)d * 64 + grp * 16 + lr4 * 4 + r) * 512 + (wu0 + v * 8 + nf * 4 + du)] = cst[nf][r];
    }
}

// ---------------- host ----------------

extern "C" void kernel_launch(void* const* d_in, const int* in_sizes, int n_in,
                              void* d_out, int out_size, void* d_ws, size_t ws_size,
                              hipStream_t stream) {
    const float* xf = (const float*)d_in[0];
    const float* xb = (const float*)d_in[1];
    const float* Wf = (const float*)d_in[2];
    const float* Uf = (const float*)d_in[3];
    const float* bf = (const float*)d_in[4];
    const float* Wb = (const float*)d_in[5];
    const float* Ub = (const float*)d_in[6];
    const float* bb = (const float*)d_in[7];
    float* out = (float*)d_out;

    char* ws = (char*)d_ws;
    size_t off = 0;
    auto alloc = [&](size_t bytes) { size_t o = off; off = (off + bytes + 255) & ~(size_t)255; return o; };
    size_t o_x16 = alloc((size_t)2 * 64 * 512 * 512 * 2);
    size_t o_wt  = alloc((size_t)2 * 2048 * 512 * 2);
    size_t o_ut  = alloc((size_t)2 * 2048 * 512 * 2);
    size_t o_cb  = alloc((size_t)2 * 64 * 512 * 4);
    size_t fixed = off;
    int CT = 512;
    while (CT > 32 && fixed + (size_t)(CT + 1) * 131072 + (size_t)2 * 64 * CT * 2048 * 2 > ws_size) CT >>= 1;
    size_t o_ring = alloc((size_t)(CT + 1) * 131072);
    size_t o_xz   = alloc((size_t)2 * 64 * CT * 2048 * 2);
    int lct = (CT == 512) ? 9 : (CT == 256) ? 8 : (CT == 128) ? 7 : (CT == 64) ? 6 : 5;

    f16* x16 = (f16*)(ws + o_x16);
    f16* wt16 = (f16*)(ws + o_wt);
    f16* ut16 = (f16*)(ws + o_ut);
    float* cb = (float*)(ws + o_cb);
    f16* ring = (f16*)(ws + o_ring);
    f16* xzp  = (f16*)(ws + o_xz);

    const int n8 = 16777216 / 8;   // per x tensor
    k_cvt<<<8192, 256, 0, stream>>>(xf, x16, n8);
    k_cvt<<<8192, 256, 0, stream>>>(xb, x16 + (size_t)16777216, n8);
    k_tcvt<<<512, 256, 0, stream>>>(Wf, wt16);
    k_tcvt<<<512, 256, 0, stream>>>(Wb, wt16 + (size_t)2048 * 512);
    k_tcvt<<<512, 256, 0, stream>>>(Uf, ut16);
    k_tcvt<<<512, 256, 0, stream>>>(Ub, ut16 + (size_t)2048 * 512);
    hipMemsetAsync(cb, 0, (size_t)2 * 64 * 512 * 4, stream);

    int nch = 512 / CT;
    int fillgrid = (int)(((size_t)(CT + 1) * 65536 / 8 + 255) / 256);
    for (int c = 0; c < nch; ++c) {
        int t0 = c * CT;
        k_proj<<<dim3(64 * CT / 128, 16, 2), 256, 0, stream>>>(x16, wt16, bf, bb, xzp, t0, CT, lct);
        if (c > 0) k_copyslot<<<32, 256, 0, stream>>>(ring, CT);
        k_fill<<<fillgrid, 256, 0, stream>>>(ring, CT, c == 0 ? 1 : 0);
        const f16* a_xz = xzp; const f16* a_ut = ut16;
        f16* a_ring = ring; float* a_cb = cb; float* a_out = out;
        int a_t0 = t0, a_ct = CT;
        void* args[7] = {&a_xz, &a_ut, &a_ring, &a_cb, &a_out, &a_t0, &a_ct};
        hipLaunchCooperativeKernel((void*)k_recur, dim3(128), dim3(256), args, 0u, stream);
    }
}

// Round 14
// 2524.947 us; speedup vs baseline: 1.3215x; 1.3215x over previous
//
#include <hip/hip_runtime.h>
#include <stdint.h>

// BiLSTM: B=64, T=512, D=512, U=512. Two independent forward-scanned LSTMs.
// Phase 0: convert inputs/weights to fp16 (weights transposed to [n][k]).
// Phase 1: xz = x @ W + b  (MFMA fp16 GEMM, per time-chunk)
// Phase 2: persistent cooperative recurrence, DATA-AS-FLAG ring buffer:
//   ring[t] = h_t, pre-filled with f16-NaN sentinel (0x7F7F bytes). Producers
//   publish via fire-and-forget 8B agent atomic stores (each granule flips
//   sentinel->data atomically; no ordering needed). Consumers poll with 8B
//   agent atomic LOADS (intrinsics -> compiler-tracked, cannot be stale),
//   each wave owns 1/4 of the tile, stages it to swizzled LDS, mid barrier,
//   all waves ds_read MFMA fragments. No inline asm, no register pinning.
//   CHAMPION (round 6, 2290us k_recur): 7 perturbations (flag protocol, big
//   WGs, single barrier, reg-xz, 16B volatile polls, XCD grouping, gate-per-
//   nf) all regressed or failed to launch (VGPR>256 silently kills
//   hipLaunchCooperativeKernel). Residual 4.5us/step is producer->MALL->
//   consumer visibility latency + compute chain, not BW/compute bound.

typedef _Float16 f16;
typedef _Float16 f16x8 __attribute__((ext_vector_type(8)));
typedef float    f32x4 __attribute__((ext_vector_type(4)));
typedef unsigned long long u64;

typedef __attribute__((address_space(1))) const void* gas_ptr;
typedef __attribute__((address_space(3))) void* las_ptr;

__device__ inline void gl_lds16(const void* g, void* l) {
    __builtin_amdgcn_global_load_lds((gas_ptr)g, (las_ptr)l, 16, 0, 0);
}

#define SENT64 0x7F7F7F7F7F7F7F7FULL

// ---------------- conversion kernels ----------------

__global__ void k_cvt(const float* __restrict__ src, f16* __restrict__ dst, int n8) {
    int i = blockIdx.x * 256 + threadIdx.x;
    if (i >= n8) return;
    const float4* s = (const float4*)src;
    float4 a = s[2 * i], b = s[2 * i + 1];
    f16x8 o = {(f16)a.x, (f16)a.y, (f16)a.z, (f16)a.w,
               (f16)b.x, (f16)b.y, (f16)b.z, (f16)b.w};
    *(f16x8*)(dst + 8 * (size_t)i) = o;
}

// src [512][2048] f32 -> dst [2048][512] f16 (transpose)
__global__ void k_tcvt(const float* __restrict__ src, f16* __restrict__ dst) {
    int tid = blockIdx.x * 256 + threadIdx.x;   // 131072 total
    int kc = tid >> 11;
    int n  = tid & 2047;
    f16x8 o;
#pragma unroll
    for (int j = 0; j < 8; ++j)
        o[j] = (f16)src[(size_t)(kc * 8 + j) * 2048 + n];
    *(f16x8*)(dst + (size_t)n * 512 + kc * 8) = o;
}

// ---------------- ring init kernels ----------------
// Cached stores; dispatch-end release flushes dirty L2 -> visible at the
// coherence point before the next dispatch's atomic loads.

__global__ void k_fill(f16* __restrict__ ring, int CT, int zero0) {
    size_t i = ((size_t)blockIdx.x * 256 + threadIdx.x) * 8;
    const size_t slot = 65536;                    // f16 per ring slot
    size_t total = (size_t)(CT + 1) * slot;
    if (i >= total) return;
    u64 fillv = SENT64;
    if (i < slot) { if (!zero0) return; fillv = 0; }
    union { u64 u[2]; f16x8 v; } t; t.u[0] = fillv; t.u[1] = fillv;
    *(f16x8*)(ring + i) = t.v;
}

__global__ void k_copyslot(f16* __restrict__ ring, int CT) {
    size_t i = (size_t)(blockIdx.x * 256 + threadIdx.x) * 8;   // 65536 f16 total
    f16x8 v = *(const f16x8*)(ring + (size_t)CT * 65536 + i);
    *(f16x8*)(ring + i) = v;
}

// ---------------- projection GEMM ----------------
// xz[d][b][tc][n] (fp16) = x16[d][b][t0+tc][:] @ WT[d][n][:] + bias[n]

__global__ __launch_bounds__(256) void k_proj(
    const f16* __restrict__ x16, const f16* __restrict__ WT,
    const float* __restrict__ bfw, const float* __restrict__ bbw,
    f16* __restrict__ xz, int t0, int CT, int lct) {
    __shared__ f16 smem[16384];
    f16* As = smem;
    f16* Bs = smem + 8192;

    const int tid = threadIdx.x;
    const int l = tid & 63, v = tid >> 6;
    const int mt = blockIdx.x, nt = blockIdx.y, d = blockIdx.z;
    const int wm = v >> 1, wn = v & 1;
    const int lr4 = l >> 4, c16 = l & 15;

    f32x4 acc[4][4];
#pragma unroll
    for (int i = 0; i < 4; ++i)
#pragma unroll
        for (int j = 0; j < 4; ++j) acc[i][j] = (f32x4)0.f;

    auto stage = [&](int kk, int buf) {
#pragma unroll
        for (int rd = 0; rd < 2; ++rd) {
            int idx = rd * 256 + tid;
            int r = idx >> 2, kp = idx & 3;
            int m = mt * 128 + r;
            int b = m >> lct, tc = m & (CT - 1);
            const f16* ga = x16 + (((size_t)(d * 64 + b) * 512 + (t0 + tc)) * 512 + kk * 32 + kp * 8);
            gl_lds16(ga, &As[buf * 4096 + (rd * 256 + v * 64) * 8]);
        }
#pragma unroll
        for (int rd = 0; rd < 2; ++rd) {
            int idx = rd * 256 + tid;
            int r = idx >> 2, kp = idx & 3;
            const f16* gb = WT + ((size_t)(d * 2048 + nt * 128 + r) * 512 + kk * 32 + kp * 8);
            gl_lds16(gb, &Bs[buf * 4096 + (rd * 256 + v * 64) * 8]);
        }
    };

    stage(0, 0);
    for (int kk = 0; kk < 16; ++kk) {
        __syncthreads();
        if (kk < 15) stage(kk + 1, (kk + 1) & 1);
        int buf = kk & 1;
        f16x8 af[4], bfr[4];
#pragma unroll
        for (int mf = 0; mf < 4; ++mf)
            af[mf] = *(const f16x8*)&As[buf * 4096 + (wm * 64 + mf * 16 + c16) * 32 + lr4 * 8];
#pragma unroll
        for (int nf = 0; nf < 4; ++nf)
            bfr[nf] = *(const f16x8*)&Bs[buf * 4096 + (wn * 64 + nf * 16 + c16) * 32 + lr4 * 8];
#pragma unroll
        for (int mf = 0; mf < 4; ++mf)
#pragma unroll
            for (int nf = 0; nf < 4; ++nf)
                acc[mf][nf] = __builtin_amdgcn_mfma_f32_16x16x32_f16(af[mf], bfr[nf], acc[mf][nf], 0, 0, 0);
    }
    __syncthreads();

    const float* bias = d ? bbw : bfw;
    float bv[4];
#pragma unroll
    for (int nf = 0; nf < 4; ++nf) bv[nf] = bias[nt * 128 + wn * 64 + nf * 16 + c16];

    f16* Cs = smem;
#pragma unroll
    for (int mf = 0; mf < 4; ++mf)
#pragma unroll
        for (int nf = 0; nf < 4; ++nf)
#pragma unroll
            for (int r = 0; r < 4; ++r) {
                int row = wm * 64 + mf * 16 + lr4 * 4 + r;
                int col = wn * 64 + nf * 16 + c16;
                Cs[row * 128 + col] = (f16)(acc[mf][nf][r] + bv[nf]);
            }
    __syncthreads();
#pragma unroll
    for (int ch = 0; ch < 8; ++ch) {
        int flat = ch * 256 + tid;
        int row = flat >> 4, cc = flat & 15;
        int m = mt * 128 + row;
        int b = m >> lct, tc = m & (CT - 1);
        f16x8 val = *(const f16x8*)&Cs[row * 128 + cc * 8];
        *(f16x8*)&xz[((size_t)(d * 64 + b) * CT + tc) * 2048 + nt * 128 + cc * 8] = val;
    }
}

// ---------------- persistent recurrence ----------------
// 128 blocks x 256 thr: block = (dir d, batch-group grp of 16 rows, unit-WG wg).
// ring slot layout: [group gidx][kb 0..15][row 0..15][32 units] f16.
// Wave v polls+stages kb 4v..4v+3 into hsm (XOR-swizzled); all waves read all kb.

__global__ __launch_bounds__(256, 1) void k_recur(
    const f16* __restrict__ xz, const f16* __restrict__ UT,
    f16* __restrict__ ring, float* __restrict__ cbuf,
    float* __restrict__ out, int t0, int CT) {
    __shared__ f16 xzsm[2][2048];
    __shared__ f16 wsm[4][128];
    __shared__ f16 hsm[8192];      // 16KB: [kb][row][32], 16B slots XOR-swizzled by (row&7)<<4

    const int tid = threadIdx.x;
    const int l = tid & 63, v = tid >> 6;
    const int bx = blockIdx.x;
    const int d   = bx >> 6;
    const int grp = (bx >> 4) & 3;
    const int wg  = bx & 15;
    const int wu0 = wg * 32;
    const int lr4 = l >> 4;          // 0..3
    const int du  = (l & 15) >> 2;   // 0..3
    const int gid = l & 3;           // gate: 0=i 1=f 2=g 3=o
    const int gidx = d * 4 + grp;

    int unitloc[2], nstd[2];
#pragma unroll
    for (int nf = 0; nf < 2; ++nf) {
        int u = wu0 + v * 8 + nf * 4 + du;
        unitloc[nf] = v * 8 + nf * 4 + du;
        nstd[nf] = gid * 512 + u;
    }

    // resident U fragments: 2 n-frags x 16 k-frags (compiler-managed)
    f16x8 Ufr[2][16];
#pragma unroll
    for (int nf = 0; nf < 2; ++nf)
#pragma unroll
        for (int kk = 0; kk < 16; ++kk)
            Ufr[nf][kk] = *(const f16x8*)&UT[((size_t)d * 2048 + nstd[nf]) * 512 + kk * 32 + lr4 * 8];

    // c state (redundant across the 4 gate lanes)
    float cst[2][4];
#pragma unroll
    for (int nf = 0; nf < 2; ++nf)
#pragma unroll
        for (int r = 0; r < 4; ++r)
            cst[nf][r] = cbuf[((size_t)d * 64 + grp * 16 + lr4 * 4 + r) * 512 + (wu0 + v * 8 + nf * 4 + du)];

    // stage xz for tl=0
    {
        int row = tid >> 4, gate = (tid >> 2) & 3, u8 = tid & 3;
        const f16* g = xz + (((size_t)(d * 64 + grp * 16 + row) * CT + 0) * 2048 + gate * 512 + wu0 + u8 * 8);
        gl_lds16(g, &xzsm[0][v * 512]);
    }

    __syncthreads();   // xzsm[0] staged

    for (int tl = 0; tl < CT; ++tl) {
        const int gt = t0 + tl;

        // z init from xz (LDS; staged by prev step's mid barrier)
        f32x4 acc0, acc1;
#pragma unroll
        for (int r = 0; r < 4; ++r) {
            acc0[r] = (float)xzsm[tl & 1][((lr4 * 4 + r) * 4 + gid) * 32 + unitloc[0]];
            acc1[r] = (float)xzsm[tl & 1][((lr4 * 4 + r) * 4 + gid) * 32 + unitloc[1]];
        }

        // prefetch next xz early (completes by this step's mid barrier)
        {
            int tnext = (tl + 1 < CT) ? tl + 1 : tl;
            int row = tid >> 4, gate = (tid >> 2) & 3, u8 = tid & 3;
            const f16* g = xz + (((size_t)(d * 64 + grp * 16 + row) * CT + tnext) * 2048 + gate * 512 + wu0 + u8 * 8);
            gl_lds16(g, &xzsm[tnext & 1][v * 512]);
        }

        // data-as-flag poll: wave v owns kb 4v..4v+3; lane covers 16B of each kb.
        // 8B atomic loads (agent scope -> coherence point); granule is sentinel
        // or final data (producer stores are 8B atomics).
        const u64* sbase = (const u64*)ring + (size_t)tl * 16384 + (size_t)gidx * 2048
                         + (size_t)(v * 4) * 128 + l * 2;
        u64 g0, g1, g2, g3, g4, g5, g6, g7;
        while (true) {
            g0 = __hip_atomic_load(sbase +   0, __ATOMIC_RELAXED, __HIP_MEMORY_SCOPE_AGENT);
            g1 = __hip_atomic_load(sbase +   1, __ATOMIC_RELAXED, __HIP_MEMORY_SCOPE_AGENT);
            g2 = __hip_atomic_load(sbase + 128, __ATOMIC_RELAXED, __HIP_MEMORY_SCOPE_AGENT);
            g3 = __hip_atomic_load(sbase + 129, __ATOMIC_RELAXED, __HIP_MEMORY_SCOPE_AGENT);
            g4 = __hip_atomic_load(sbase + 256, __ATOMIC_RELAXED, __HIP_MEMORY_SCOPE_AGENT);
            g5 = __hip_atomic_load(sbase + 257, __ATOMIC_RELAXED, __HIP_MEMORY_SCOPE_AGENT);
            g6 = __hip_atomic_load(sbase + 384, __ATOMIC_RELAXED, __HIP_MEMORY_SCOPE_AGENT);
            g7 = __hip_atomic_load(sbase + 385, __ATOMIC_RELAXED, __HIP_MEMORY_SCOPE_AGENT);
            unsigned bad = (g0 == SENT64) | (g1 == SENT64) | (g2 == SENT64) | (g3 == SENT64)
                         | (g4 == SENT64) | (g5 == SENT64) | (g6 == SENT64) | (g7 == SENT64);
            if (!__any(bad)) break;
            __builtin_amdgcn_s_sleep(1);
        }

        // stage own quarter into LDS (swizzled 16B slots)
        {
            u64 gg[4][2] = {{g0, g1}, {g2, g3}, {g4, g5}, {g6, g7}};
#pragma unroll
            for (int jj = 0; jj < 4; ++jj) {
                union { u64 u[2]; f16x8 v8; } t; t.u[0] = gg[jj][0]; t.u[1] = gg[jj][1];
                int byte = (v * 4 + jj) * 1024 + l * 16;
                byte ^= ((l >> 2) & 7) << 4;
                *(f16x8*)((char*)hsm + byte) = t.v8;
            }
        }
        __syncthreads();   // h tile staged; xz prefetch drained

        // z += h @ U  (fragments from LDS, bank-spread by swizzle)
#pragma unroll
        for (int j = 0; j < 16; ++j) {
            int byte = j * 1024 + (l & 15) * 64 + lr4 * 16;
            byte ^= (l & 7) << 4;
            f16x8 a = *(const f16x8*)((const char*)hsm + byte);
            acc0 = __builtin_amdgcn_mfma_f32_16x16x32_f16(a, Ufr[0][j], acc0, 0, 0, 0);
            acc1 = __builtin_amdgcn_mfma_f32_16x16x32_f16(a, Ufr[1][j], acc1, 0, 0, 0);
        }

        // own-gate activation (gate 2 = tanh, else sigmoid)
        float act[2][4];
#pragma unroll
        for (int nf = 0; nf < 2; ++nf)
#pragma unroll
            for (int r = 0; r < 4; ++r) {
                float z = nf ? acc1[r] : acc0[r];
                float zz = (gid == 2) ? 2.f * z : z;
                float r0 = 1.f / (1.f + __expf(-zz));
                act[nf][r] = (gid == 2) ? 2.f * r0 - 1.f : r0;
            }

        // exchange gates among the 4 adjacent lanes; update c; gate0 computes h
#pragma unroll
        for (int nf = 0; nf < 2; ++nf)
#pragma unroll
            for (int r = 0; r < 4; ++r) {
                float a0 = act[nf][r];
                float a1 = __shfl_xor(a0, 1);
                float a2 = __shfl_xor(a0, 2);
                float a3 = __shfl_xor(a0, 3);
                int mi = gid, mf_ = gid ^ 1, mg = gid ^ 2, mo = gid ^ 3;
                float iv = mi == 0 ? a0 : mi == 1 ? a1 : mi == 2 ? a2 : a3;
                float fv = mf_ == 0 ? a0 : mf_ == 1 ? a1 : mf_ == 2 ? a2 : a3;
                float gv = mg == 0 ? a0 : mg == 1 ? a1 : mg == 2 ? a2 : a3;
                float ov = mo == 0 ? a0 : mo == 1 ? a1 : mo == 2 ? a2 : a3;
                float cn = fv * cst[nf][r] + iv * gv;
                cst[nf][r] = cn;
                if (gid == 0) {
                    float th = copysignf(1.f - 2.f / (__expf(2.f * fabsf(cn)) + 1.f), cn);
                    wsm[v][(nf * 4 + du) * 16 + lr4 * 4 + r] = (f16)(ov * th);
                }
            }

        // lanes 0..15 gather their batch-row; publish h (fire-and-forget 8B atomics)
        if (l < 16) {
            f16x8 hv8;
#pragma unroll
            for (int j = 0; j < 8; ++j) hv8[j] = wsm[v][j * 16 + l];
            f16* dst = ring + (size_t)(tl + 1) * 65536 + (size_t)gidx * 8192
                     + ((size_t)wg * 16 + l) * 32 + v * 8;
            union { u64 u[2]; f16x8 v8; } t; t.v8 = hv8;
            __hip_atomic_store((u64*)dst + 0, t.u[0], __ATOMIC_RELAXED, __HIP_MEMORY_SCOPE_AGENT);
            __hip_atomic_store((u64*)dst + 1, t.u[1], __ATOMIC_RELAXED, __HIP_MEMORY_SCOPE_AGENT);
            size_t ob = ((size_t)(grp * 16 + l) * 512 + gt) * 1024 + d * 512 + wu0 + v * 8;
            float4 o0 = {(float)hv8[0], (float)hv8[1], (float)hv8[2], (float)hv8[3]};
            float4 o1 = {(float)hv8[4], (float)hv8[5], (float)hv8[6], (float)hv8[7]};
            *(float4*)&out[ob] = o0;
            *(float4*)&out[ob + 4] = o1;
        }

        __syncthreads();   // wsm/hsm reuse + xzsm parity hand-off
    }

    // persist c for next chunk
    if (gid == 0) {
#pragma unroll
        for (int nf = 0; nf < 2; ++nf)
#pragma unroll
            for (int r = 0; r < 4; ++r)
                cbuf[((size_t)d * 64 + grp * 16 + lr4 * 4 + r) * 512 + (wu0 + v * 8 + nf * 4 + du)] = cst[nf][r];
    }
}

// ---------------- host ----------------

extern "C" void kernel_launch(void* const* d_in, const int* in_sizes, int n_in,
                              void* d_out, int out_size, void* d_ws, size_t ws_size,
                              hipStream_t stream) {
    const float* xf = (const float*)d_in[0];
    const float* xb = (const float*)d_in[1];
    const float* Wf = (const float*)d_in[2];
    const float* Uf = (const float*)d_in[3];
    const float* bf = (const float*)d_in[4];
    const float* Wb = (const float*)d_in[5];
    const float* Ub = (const float*)d_in[6];
    const float* bb = (const float*)d_in[7];
    float* out = (float*)d_out;

    char* ws = (char*)d_ws;
    size_t off = 0;
    auto alloc = [&](size_t bytes) { size_t o = off; off = (off + bytes + 255) & ~(size_t)255; return o; };
    size_t o_x16 = alloc((size_t)2 * 64 * 512 * 512 * 2);
    size_t o_wt  = alloc((size_t)2 * 2048 * 512 * 2);
    size_t o_ut  = alloc((size_t)2 * 2048 * 512 * 2);
    size_t o_cb  = alloc((size_t)2 * 64 * 512 * 4);
    size_t fixed = off;
    int CT = 512;
    while (CT > 32 && fixed + (size_t)(CT + 1) * 131072 + (size_t)2 * 64 * CT * 2048 * 2 > ws_size) CT >>= 1;
    size_t o_ring = alloc((size_t)(CT + 1) * 131072);
    size_t o_xz   = alloc((size_t)2 * 64 * CT * 2048 * 2);
    int lct = (CT == 512) ? 9 : (CT == 256) ? 8 : (CT == 128) ? 7 : (CT == 64) ? 6 : 5;

    f16* x16 = (f16*)(ws + o_x16);
    f16* wt16 = (f16*)(ws + o_wt);
    f16* ut16 = (f16*)(ws + o_ut);
    float* cb = (float*)(ws + o_cb);
    f16* ring = (f16*)(ws + o_ring);
    f16* xzp  = (f16*)(ws + o_xz);

    const int n8 = 16777216 / 8;   // per x tensor
    k_cvt<<<8192, 256, 0, stream>>>(xf, x16, n8);
    k_cvt<<<8192, 256, 0, stream>>>(xb, x16 + (size_t)16777216, n8);
    k_tcvt<<<512, 256, 0, stream>>>(Wf, wt16);
    k_tcvt<<<512, 256, 0, stream>>>(Wb, wt16 + (size_t)2048 * 512);
    k_tcvt<<<512, 256, 0, stream>>>(Uf, ut16);
    k_tcvt<<<512, 256, 0, stream>>>(Ub, ut16 + (size_t)2048 * 512);
    hipMemsetAsync(cb, 0, (size_t)2 * 64 * 512 * 4, stream);

    int nch = 512 / CT;
    int fillgrid = (int)(((size_t)(CT + 1) * 65536 / 8 + 255) / 256);
    for (int c = 0; c < nch; ++c) {
        int t0 = c * CT;
        k_proj<<<dim3(64 * CT / 128, 16, 2), 256, 0, stream>>>(x16, wt16, bf, bb, xzp, t0, CT, lct);
        if (c > 0) k_copyslot<<<32, 256, 0, stream>>>(ring, CT);
        k_fill<<<fillgrid, 256, 0, stream>>>(ring, CT, c == 0 ? 1 : 0);
        const f16* a_xz = xzp; const f16* a_ut = ut16;
        f16* a_ring = ring; float* a_cb = cb; float* a_out = out;
        int a_t0 = t0, a_ct = CT;
        void* args[7] = {&a_xz, &a_ut, &a_ring, &a_cb, &a_out, &a_t0, &a_ct};
        hipLaunchCooperativeKernel((void*)k_recur, dim3(128), dim3(256), args, 0u, stream);
    }
}